// Round 9
// baseline (175.092 us; speedup 1.0000x reference)
//
#include <hip/hip_runtime.h>
#include <hip/hip_bf16.h>
#include <math.h>

// Stickbreaking attention, bf16 MFMA, flash-style suffix-scan carry.
// B=2 H=16 S=1024 D=64.
// Round-9 = round-8 with the product-scan off-by-one FIXED:
//   reference's cum_weight = tril(ones) INCLUDES the diagonal, so
//   w[i,k] = z_k * exp(sum_{j=k..i} lb_j) = z_k * s_k * prod_{j>k} s_j
//   with s = sigmoid(-l).  Round-8 used the EXCLUSIVE product (missing s_k)
//   -> weights too large by 1/s_k, absmax 3.73.  Now: inclusive suffix
//   products p_r = s_r * p_{r+1}; zw[r] = z_r * p_r; R = p0 (unchanged).
// Structure (from rounds 6-8):
//   * prep writes K->(hi,lo) and V->V^T bf16 frag-order blobs to d_ws; lane's
//     16 B IS its MFMA fragment; main reads with coalesced global_load_dwordx4
//     (L1/L2-resident, XCD-swizzled); no LDS staging, no __syncthreads in main.
//   * split-K 2-way: hi block covers [nl..qt] (incl. diagonal), lo [0..nl);
//     merge: out = O_hi + exp(C_hi)*O_lo.  Complementary pairing balances CUs.
//   * software-pipelined K frags (loaded after GEMM1 consumes previous; fly
//     through scan+GEMM2); vb loads fly through GEMM1.
//   * product-domain scan: 2 transcendentals/elem (exp, rcp); per-tile totals
//     through log once (Crow += logf(P)).  Underflow coincides with fp32
//     reference's exp() flush -> error-neutral.  fminf(l,80) guards overflow;
//     masked elems l=-1e30 -> s=1, z=0.
// GEMM1 split-precision bf16 (3 MFMAs -> fp32-accurate logits); GEMM2 plain
// bf16. mfma_f32_16x16x32_bf16 layouts per m89/m120: A[m=lane&15][k=q4*8+e],
// B[k][n=lane&15], C/D col=lane&15, row=q4*4+reg.

typedef __attribute__((ext_vector_type(8))) short short8;
typedef __attribute__((ext_vector_type(4))) short short4v;
typedef __attribute__((ext_vector_type(4))) float f32x4;

#define WPITCH 72        // Ws row pitch (shorts): b64 writes / b128 reads bank-uniform
#define BLOB_SH 12288    // shorts per tile blob: Kh 4096 | Kl 4096 | Vt 4096 (24576 B)
#define NBLOB 512        // 32 heads x 16 tiles
#define VP 66            // prep V-transpose LDS pitch (floats)

__device__ inline short bf16r(float x) {
    __hip_bfloat16 h = __float2bfloat16(x);   // RNE
    return *(short*)&h;
}
__device__ inline float bf16f(short s) {
    union { unsigned u; float f; } c;
    c.u = ((unsigned)(unsigned short)s) << 16;
    return c.f;
}

// ---------------- prep: frag-order blobs in ws ----------------
__global__ __launch_bounds__(256) void stickbreak_prep(
    const float* __restrict__ Kg, const float* __restrict__ Vg,
    short* __restrict__ ws)
{
    __shared__ float Vlds[64 * VP];

    const int t = threadIdx.x;
    const int n = blockIdx.x;                 // n = bh*16 + kt (strides collapse)
    const float* kp = Kg + (size_t)n * 4096;
    const float* vp = Vg + (size_t)n * 4096;
    short* blob = ws + (size_t)n * BLOB_SH;

    const int lane = t & 63;
    const int l16 = lane & 15;
    const int q4 = lane >> 4;
    const int s0 = t >> 6;                    // 0..3

    // stage V into LDS (coalesced float4 global reads, float2 LDS writes)
    {
        const int row = t >> 2;
        const int cb = (t & 3) << 4;
        #pragma unroll
        for (int c = 0; c < 4; ++c) {
            const float4 f = *(const float4*)(vp + row * 64 + cb + 4 * c);
            *(float2*)&Vlds[row * VP + cb + 4 * c]     = make_float2(f.x, f.y);
            *(float2*)&Vlds[row * VP + cb + 4 * c + 2] = make_float2(f.z, f.w);
        }
    }

    // K hi/lo fragments (independent of LDS; overlaps the barrier)
    #pragma unroll
    for (int w = 0; w < 2; ++w) {
        const int s  = s0 + 4 * w;            // 0..7
        const int nt = s >> 1;
        const int ks = s & 1;
        const float* src = kp + (16 * nt + l16) * 64 + 32 * ks + 8 * q4;
        const float4 f0 = *(const float4*)src;
        const float4 f1 = *(const float4*)(src + 4);
        float a[8] = {f0.x, f0.y, f0.z, f0.w, f1.x, f1.y, f1.z, f1.w};
        short8 h, l;
        #pragma unroll
        for (int e = 0; e < 8; ++e) {
            h[e] = bf16r(a[e]);
            l[e] = bf16r(a[e] - bf16f(h[e]));
        }
        *(short8*)&blob[s * 512 + lane * 8]        = h;
        *(short8*)&blob[4096 + s * 512 + lane * 8] = l;
    }

    __syncthreads();

    // transposed V reads -> frag-order bf16 blob
    #pragma unroll
    for (int w = 0; w < 2; ++w) {
        const int s  = s0 + 4 * w;
        const int nt = s >> 1;
        const int ks = s & 1;
        const int d  = 16 * nt + l16;
        const int jb = 32 * ks + 8 * q4;
        short8 wv8;
        #pragma unroll
        for (int e = 0; e < 8; ++e) wv8[e] = bf16r(Vlds[(jb + e) * VP + d]);
        *(short8*)&blob[8192 + s * 512 + lane * 8] = wv8;
    }
}

// ---------------- main (barrier-free, split-K halves, pipelined) ----------------
// part layout (floats): part[g*8192 + 0..4095] = O_hi, +4096..8191 = O_lo,
//                       part[NBLOB*8192 + g*64 + i] = C_hi row totals; g = bh*16+qt.
__global__ __launch_bounds__(256, 4) void stickbreak_main(
    const float* __restrict__ Qg, const short* __restrict__ ws,
    float* __restrict__ part)
{
    __shared__ __align__(16) short Ws[64 * WPITCH];   // 9216 B, wave-local rows

    const int t = threadIdx.x;
    const int n = blockIdx.x;                 // 0..1023
    const int half = n >> 9;                  // 0 = hi (diag side), 1 = lo
    const int m = n & 511;
    // m&7 fastest -> q-tiles/halves of one head share an XCD (blob L2 reuse).
    const int bh = (m & 7) + 8 * (m >> 7);    // 0..31
    const int qr = (m >> 3) & 15;
    const int qt = (m >> 8) ? (15 - qr) : qr; // complementary length pairing
    const int nl = (qt + 1) >> 1;             // lo tile count: tiles [0, nl)
    const int kstart = half ? (nl - 1) : qt;
    const int kend   = half ? 0 : nl;

    const size_t hbase = (size_t)bh * 1024 * 64;
    const float* qp = Qg + hbase + (size_t)qt * 64 * 64;
    const short* blobs = ws + (size_t)bh * 16 * BLOB_SH;
    const int g = bh * 16 + qt;
    float* opart = part + (size_t)g * 8192 + (half ? 4096 : 0);
    float* Cb = part + (size_t)NBLOB * 8192;

    const int lane = t & 63;
    const int wv   = t >> 6;      // wave 0..3 -> q-rows [16wv, 16wv+16)
    const int l16  = lane & 15;
    const int q4   = lane >> 4;   // quad 0..3

    // ---- Q fragments straight to registers (loop-invariant, hi/lo split) ----
    short8 qfh[2], qfl[2];
    {
        const float* qrow = qp + (16 * wv + l16) * 64;
        #pragma unroll
        for (int ks = 0; ks < 2; ++ks) {
            const int base = 32 * ks + 8 * q4;
            const float4 f0 = *(const float4*)(qrow + base);
            const float4 f1 = *(const float4*)(qrow + base + 4);
            float a[8] = {f0.x, f0.y, f0.z, f0.w, f1.x, f1.y, f1.z, f1.w};
            #pragma unroll
            for (int j = 0; j < 8; ++j) {
                const short hi = bf16r(a[j]);
                qfh[ks][j] = hi;
                qfl[ks][j] = bf16r(a[j] - bf16f(hi));
            }
        }
    }

    f32x4 Oacc[4];
    #pragma unroll
    for (int i = 0; i < 4; ++i) Oacc[i] = (f32x4){0.f, 0.f, 0.f, 0.f};
    float Crow = 0.f;    // carried log-domain suffix sum for q-row 16wv+l16

    // ---- preload first K-tile fragments ----
    short8 kh[8], kl[8];
    if (kstart >= kend) {
        const short* b0 = blobs + (size_t)kstart * BLOB_SH;
        #pragma unroll
        for (int s = 0; s < 8; ++s) {
            kh[s] = *(const short8*)&b0[s * 512 + lane * 8];
            kl[s] = *(const short8*)&b0[4096 + s * 512 + lane * 8];
        }
    }

    for (int kt = kstart; kt >= kend; --kt) {
        const short* blob = blobs + (size_t)kt * BLOB_SH;

        // ---- issue V fragment loads (fly through GEMM1) ----
        short8 vb[8];
        #pragma unroll
        for (int s = 0; s < 8; ++s)
            vb[s] = *(const short8*)&blob[8192 + s * 512 + lane * 8];

        // ---- GEMM1: S^T = K Q^T on preloaded kh/kl (split precision) ----
        // D[m=j][n=i]: col i = l16, row j = 16nt + 4q4 + reg.
        f32x4 Sacc[4];
        #pragma unroll
        for (int i = 0; i < 4; ++i) Sacc[i] = (f32x4){0.f, 0.f, 0.f, 0.f};
        #pragma unroll
        for (int ks = 0; ks < 2; ++ks) {
            #pragma unroll
            for (int nt = 0; nt < 4; ++nt) {
                const int s = nt * 2 + ks;
                Sacc[nt] = __builtin_amdgcn_mfma_f32_16x16x32_bf16(kh[s], qfh[ks], Sacc[nt], 0, 0, 0);
                Sacc[nt] = __builtin_amdgcn_mfma_f32_16x16x32_bf16(kl[s], qfh[ks], Sacc[nt], 0, 0, 0);
                Sacc[nt] = __builtin_amdgcn_mfma_f32_16x16x32_bf16(kh[s], qfl[ks], Sacc[nt], 0, 0, 0);
            }
        }

        // ---- prefetch next K-tile fragments (fly through scan + GEMM2) ----
        if (kt > kend) {
            const short* nb = blobs + (size_t)(kt - 1) * BLOB_SH;
            #pragma unroll
            for (int s = 0; s < 8; ++s) {
                kh[s] = *(const short8*)&nb[s * 512 + lane * 8];
                kl[s] = *(const short8*)&nb[4096 + s * 512 + lane * 8];
            }
        }

        // ---- product-domain scan (lane owns q-row i=16wv+l16; j = 16nt+4q4+reg) ----
        // w_j = z_j * p_j * (cross-run/cross-lane suffix) * E, p_j INCLUSIVE.
        const bool diag = (half == 0) && (kt == qt);
        const int irow = 16 * wv + l16;
        const float E = __expf(Crow);            // carry factor, 1 exp/tile
        float zw[4][4];                          // z_j * within-run INCLUSIVE suffix product
        float R[4];                              // run total products
        #pragma unroll
        for (int nt = 0; nt < 4; ++nt) {
            float sg[4], zz[4];
            #pragma unroll
            for (int reg = 0; reg < 4; ++reg) {
                float l = Sacc[nt][reg] * 0.125f;
                if (diag && (16 * nt + 4 * q4 + reg > irow)) l = -1e30f;  // mask
                l = fminf(l, 80.f);                               // exp overflow guard
                const float el = __expf(l);
                const float s  = __builtin_amdgcn_rcpf(1.f + el); // sigmoid(-l) = exp(lb)
                sg[reg] = s;
                zz[reg] = el * s;                                  // sigmoid(l)
            }
            const float p3 = sg[3];
            const float p2 = sg[2] * p3;
            const float p1 = sg[1] * p2;
            const float p0 = sg[0] * p1;         // run-inclusive product
            zw[nt][0] = zz[0] * p0;              // diagonal included: z_k * s_k * ...
            zw[nt][1] = zz[1] * p1;
            zw[nt][2] = zz[2] * p2;
            zw[nt][3] = zz[3] * p3;
            R[nt] = p0;
        }
        // cross-lane suffix products over q4 (stride-16 lanes), then over nt
        float exq[4], Tn[4];
        #pragma unroll
        for (int nt = 0; nt < 4; ++nt) {
            float gq = R[nt];
            float u = __shfl_down(gq, 16, 64); if (q4 < 3) gq *= u;
            u = __shfl_down(gq, 32, 64);       if (q4 < 2) gq *= u;
            float ex_ = __shfl_down(gq, 16, 64);             // exclusive over q4' > q4
            exq[nt] = (q4 < 3) ? ex_ : 1.f;
            Tn[nt]  = __shfl(gq, l16, 64);                   // nt total (q4=0 lane, same i)
        }
        const float TSa1 = Tn[2] * Tn[3];
        const float TSa0 = Tn[1] * TSa1;
        const float TSa[4] = { TSa0, TSa1, Tn[3], 1.f };
        #pragma unroll
        for (int nt = 0; nt < 4; ++nt) {
            const float mfac = exq[nt] * TSa[nt] * E;
            short4v w4;
            #pragma unroll
            for (int reg = 0; reg < 4; ++reg)
                w4[reg] = bf16r(zw[nt][reg] * mfac);
            *(short4v*)&Ws[irow * WPITCH + 16 * nt + 4 * q4] = w4;   // wave-local rows
        }
        Crow += __logf(Tn[0] * TSa0);            // full tile row total, 1 log/tile

        // ---- GEMM2: O += W V  (wa via wave-local LDS round-trip) ----
        #pragma unroll
        for (int ks = 0; ks < 2; ++ks) {
            const short8 wa = *(const short8*)&Ws[(16 * wv + l16) * WPITCH + 32 * ks + 8 * q4];
            #pragma unroll
            for (int dt = 0; dt < 4; ++dt) {
                Oacc[dt] = __builtin_amdgcn_mfma_f32_16x16x32_bf16(wa, vb[dt * 2 + ks], Oacc[dt], 0, 0, 0);
            }
        }
    }

    // ---- epilogue: C-layout scatter to partial buffer; hi also writes C ----
    #pragma unroll
    for (int dt = 0; dt < 4; ++dt)
        #pragma unroll
        for (int r = 0; r < 4; ++r)
            opart[(16 * wv + 4 * q4 + r) * 64 + 16 * dt + l16] = Oacc[dt][r];
    if (half == 0 && q4 == 0)
        Cb[(size_t)g * 64 + 16 * wv + l16] = Crow;
}

// ---------------- merge: out = O_hi + exp(C_hi) * O_lo ----------------
__global__ __launch_bounds__(256) void stickbreak_merge(
    const float* __restrict__ part, float* __restrict__ out)
{
    const int g = blockIdx.x;                 // 0..511 (= bh*16+qt)
    const int t = threadIdx.x;
    const int i = t >> 2;                     // row 0..63
    const int c0 = (t & 3) << 4;              // col base
    const float* Ohi = part + (size_t)g * 8192 + i * 64 + c0;
    const float* Olo = Ohi + 4096;
    const float e = __expf(part[(size_t)NBLOB * 8192 + (size_t)g * 64 + i]);
    float* o = out + (size_t)g * 4096 + i * 64 + c0;
    #pragma unroll
    for (int c = 0; c < 4; ++c) {
        const float4 a = ((const float4*)Ohi)[c];
        const float4 b = ((const float4*)Olo)[c];
        float4 r;
        r.x = fmaf(e, b.x, a.x);
        r.y = fmaf(e, b.y, a.y);
        r.z = fmaf(e, b.z, a.z);
        r.w = fmaf(e, b.w, a.w);
        ((float4*)o)[c] = r;
    }
}

extern "C" void kernel_launch(void* const* d_in, const int* in_sizes, int n_in,
                              void* d_out, int out_size, void* d_ws, size_t ws_size,
                              hipStream_t stream) {
    const float* q = (const float*)d_in[0];
    const float* k = (const float*)d_in[1];
    const float* v = (const float*)d_in[2];
    float* out = (float*)d_out;
    short* ws = (short*)d_ws;
    float* part = (float*)(ws + (size_t)NBLOB * BLOB_SH);   // partials after 12.6 MB blobs
    stickbreak_prep<<<dim3(512), dim3(256), 0, stream>>>(k, v, ws);
    stickbreak_main<<<dim3(1024), dim3(256), 0, stream>>>(q, ws, part);
    stickbreak_merge<<<dim3(512), dim3(256), 0, stream>>>(part, out);
}